// Round 10
// baseline (426.282 us; speedup 1.0000x reference)
//
#include <hip/hip_runtime.h>
#include <stdint.h>
#include <math.h>

#define BN_EPS 1e-3f

// bit-pack weight signs: bit=1 <=> w<0; layout [(tap*CINW+wi)][COUT]
template <int CIN, int COUT>
__device__ inline void packw_item(const float* __restrict__ w, uint32_t* __restrict__ wp, int idx) {
    const int CINW = CIN / 32;
    int co = idx % COUT;
    int t2 = idx / COUT;
    int wi = t2 % CINW;
    int tap = t2 / CINW;
    uint32_t word = 0;
#pragma unroll
    for (int bb = 0; bb < 32; bb++) {
        float val = w[((tap * CIN) + wi * 32 + bb) * COUT + co];
        word |= (uint32_t)(val < 0.f) << bb;
    }
    wp[idx] = word;
}

// sign(bn(v)) < 0  <=>  v < m - b*sqrt(var+eps)   (rsqrt > 0 always)
__device__ inline float mk_thr(const float* m, const float* v, const float* b, int c) {
    return (float)((double)m[c] - (double)b[c] * sqrt((double)v[c] + (double)BN_EPS));
}

// ============================================================
// Kernel 1 = conv1 (blocks 0..2047) + weight-prep (blocks 2048..2143).
// conv1: conv(x, sign(w1), VALID) + maxpool2 + bn + sign -> packed u32.
// 128-thread blocks (2 waves), tile 16x8 pooled pixels, LDS 7.5 KB ->
// 16 blocks/CU = 8 waves/SIMD (VGPR<=64 enforced by launch_bounds(128,8);
// R9 measured 60 for this body). Thread = 1 pooled pixel x 32 ch.
// ============================================================
__global__ __launch_bounds__(128, 8) void conv1_k(
    const float* __restrict__ x,  const float* __restrict__ w1,
    const float* __restrict__ m1, const float* __restrict__ v1, const float* __restrict__ b1,
    const float* __restrict__ w2, const float* __restrict__ m2, const float* __restrict__ v2,
    const float* __restrict__ b2,
    const float* __restrict__ w3, const float* __restrict__ m3, const float* __restrict__ v3,
    const float* __restrict__ b3,
    const float* __restrict__ w4,
    uint32_t* __restrict__ y1p,
    uint32_t* __restrict__ w2p, float* __restrict__ thr2,
    uint32_t* __restrict__ w3p, float* __restrict__ thr3,
    uint32_t* __restrict__ w4p) {

    if (blockIdx.x >= 2048) {          // ---- weight-prep blocks ----
        int j = (blockIdx.x - 2048) * 128 + threadIdx.x;
        if (j < 576) { packw_item<32, 64>(w2, w2p, j); }
        else if ((j -= 576) < 64) { thr2[j] = mk_thr(m2, v2, b2, j); }
        else if ((j -= 64) < 2304) { packw_item<64, 128>(w3, w3p, j); }
        else if ((j -= 2304) < 128) { thr3[j] = mk_thr(m3, v3, b3, j); }
        else if ((j -= 128) < 9216) { packw_item<128, 256>(w4, w4p, j); }
        return;
    }

    __shared__ float xt[18 * 104];     // 18 input rows x 102 col-floats (pad 104)
    __shared__ float th_lds[32];

    int tile = blockIdx.x;
    int tx = tile & 3;                 // 4 col-tiles of 16 pooled px
    int ty = (tile >> 2) & 7;          // 8 row-tiles of 8 pooled px
    int n  = tile >> 5;
    int ph0 = ty * 8, pw0 = tx * 16;
    int r0 = 2 * ph0;
    int cf0 = pw0 * 6;                 // col-float origin (x row = 384 floats)

    for (int i = threadIdx.x; i < 18 * 102; i += 128) {
        int r = i / 102, c = i % 102;
        int gr = r0 + r, gcf = cf0 + c;
        float vv = 0.f;
        if (gr < 128 && gcf < 384)
            vv = x[(size_t)(n * 128 + gr) * 384 + gcf];
        xt[r * 104 + c] = vv;
    }
    if (threadIdx.x < 32)
        th_lds[threadIdx.x] = mk_thr(m1, v1, b1, threadIdx.x);

    int lane = threadIdx.x & 63;

    // w1 sign masks -> SGPRs via ballot (lanes 32-63 duplicate; low 32 bits valid)
    uint32_t um[27];
#pragma unroll
    for (int t = 0; t < 27; t++)
        um[t] = (uint32_t)__ballot(w1[t * 32 + (lane & 31)] < 0.f);

    __syncthreads();

    int px = threadIdx.x & 15, py = threadIdx.x >> 4;   // 16 x 8
    int ph = ph0 + py, pw = pw0 + px;

    // 4x4x3 input window in regs (float2 LDS reads, 8B aligned)
    float win[48];
#pragma unroll
    for (int r = 0; r < 4; r++) {
        const float2* bp = (const float2*)&xt[(2 * py + r) * 104 + 6 * px];
#pragma unroll
        for (int q = 0; q < 6; q++) {
            float2 f2 = bp[q];
            win[r * 12 + 2 * q]     = f2.x;
            win[r * 12 + 2 * q + 1] = f2.y;
        }
    }

    uint32_t word = 0;
#pragma unroll
    for (int cg = 0; cg < 2; cg++) {            // 16 channels per group
        float a[16][4];
#pragma unroll
        for (int j = 0; j < 16; j++)
#pragma unroll
            for (int p = 0; p < 4; p++) a[j][p] = 0.f;
#pragma unroll
        for (int kh = 0; kh < 3; kh++)
#pragma unroll
            for (int kw = 0; kw < 3; kw++)
#pragma unroll
                for (int ci = 0; ci < 3; ci++) {
                    int tap = (kh * 3 + kw) * 3 + ci;
                    float x00 = win[kh * 12 + kw * 3 + ci];
                    float x01 = win[kh * 12 + (kw + 1) * 3 + ci];
                    float x10 = win[(kh + 1) * 12 + kw * 3 + ci];
                    float x11 = win[(kh + 1) * 12 + (kw + 1) * 3 + ci];
                    uint32_t mw = um[tap] >> (cg * 16);
#pragma unroll
                    for (int j = 0; j < 16; j++) {
                        float w = ((mw >> j) & 1u) ? -1.f : 1.f;  // uniform mask select
                        a[j][0] += x00 * w;
                        a[j][1] += x01 * w;
                        a[j][2] += x10 * w;
                        a[j][3] += x11 * w;
                    }
                }
#pragma unroll
        for (int j = 0; j < 16; j++) {
            float mx = fmaxf(fmaxf(a[j][0], a[j][1]), fmaxf(a[j][2], a[j][3]));
            int ch = cg * 16 + j;
            word |= (uint32_t)(mx < th_lds[ch]) << ch;
        }
    }

    if (ph < 63 && pw < 63)
        y1p[(n * 63 + ph) * 63 + pw] = word;
}

// ============================================================
// Layer 2: bconv(SAME, 63x63, CIN=32) + maxpool2 + bn + sign -> packed
// One wave per 4-pixel row group; lane = co. Window = 4x10 uniform words.
// ============================================================
__global__ __launch_bounds__(256) void bconv2(const uint32_t* __restrict__ y1p,
                                              const uint32_t* __restrict__ w2p,
                                              const float* __restrict__ thr2,
                                              uint2* __restrict__ y2p) {
    int gw = __builtin_amdgcn_readfirstlane(blockIdx.x * 4 + (threadIdx.x >> 6));
    int lane = threadIdx.x & 63;
    int pwg = gw & 7;          // pixel group: pw = 4*pwg + p
    int t = gw >> 3;
    int ph = t % 31;
    int n = t / 31;

    uint32_t wq[9];
#pragma unroll
    for (int tap = 0; tap < 9; tap++) wq[tap] = w2p[tap * 64 + lane];
    float th = thr2[lane];

    uint2 res[4];
    if (ph > 0 && pwg > 0) {
        int row0 = 2 * ph - 1, col0 = 8 * pwg - 1;
        uint32_t win[4][10];
#pragma unroll
        for (int r = 0; r < 4; r++)
#pragma unroll
            for (int c = 0; c < 10; c++)
                win[r][c] = y1p[(n * 63 + row0 + r) * 63 + min(col0 + c, 62)];
#pragma unroll
        for (int p = 0; p < 4; p++) {
            int a0 = 0, a1 = 0, a2 = 0, a3 = 0;
#pragma unroll
            for (int kh = 0; kh < 3; kh++)
#pragma unroll
                for (int kw = 0; kw < 3; kw++) {
                    uint32_t w = wq[kh * 3 + kw];
                    a0 += __popc(win[kh][2 * p + kw] ^ w);
                    a1 += __popc(win[kh][2 * p + kw + 1] ^ w);
                    a2 += __popc(win[kh + 1][2 * p + kw] ^ w);
                    a3 += __popc(win[kh + 1][2 * p + kw + 1] ^ w);
                }
            int best = 288 - 2 * min(min(a0, a1), min(a2, a3));
            unsigned long long bal = __ballot((float)best < th);
            res[p] = make_uint2((uint32_t)bal, (uint32_t)(bal >> 32));
        }
    } else {
#pragma unroll
        for (int p = 0; p < 4; p++) {
            int pw = 4 * pwg + p;
            int best = -1000000;
            if (pw < 31) {
#pragma unroll
                for (int dy = 0; dy < 2; dy++)
#pragma unroll
                    for (int dx = 0; dx < 2; dx++) {
                        int oh = 2 * ph + dy, ow = 2 * pw + dx;
                        int acc = 0, K = 0;
                        for (int kh = 0; kh < 3; kh++) {
                            int ih = oh - 1 + kh;
                            if (ih < 0 || ih >= 63) continue;
                            for (int kw = 0; kw < 3; kw++) {
                                int iw = ow - 1 + kw;
                                if (iw < 0 || iw >= 63) continue;
                                acc += __popc(y1p[(n * 63 + ih) * 63 + iw] ^ wq[kh * 3 + kw]);
                                K += 32;
                            }
                        }
                        best = max(best, K - 2 * acc);
                    }
            }
            unsigned long long bal = __ballot((float)best < th);
            res[p] = make_uint2((uint32_t)bal, (uint32_t)(bal >> 32));
        }
    }
    uint2 rr = res[0];
    if (lane == 1) rr = res[1];
    if (lane == 2) rr = res[2];
    if (lane == 3) rr = res[3];
    int pws = 4 * pwg + lane;
    if (lane < 4 && pws < 31)
        y2p[(n * 31 + ph) * 31 + pws] = rr;
}

// ============================================================
// Layer 3: bconv(SAME, 31x31, CIN=64) + maxpool2 + bn + sign -> packed
// Wave per (2-pixel group, co-half). Window = 4x6 uint2 uniform words.
// ============================================================
__global__ __launch_bounds__(256) void bconv3(const uint2* __restrict__ y2p,
                                              const uint32_t* __restrict__ w3p,
                                              const float* __restrict__ thr3,
                                              uint32_t* __restrict__ y3p) {
    int gw = __builtin_amdgcn_readfirstlane(blockIdx.x * 4 + (threadIdx.x >> 6));
    int lane = threadIdx.x & 63;
    int half = gw & 1;
    int t = gw >> 1;
    int pwg = t & 7;           // pw = 2*pwg + p
    t >>= 3;
    int ph = t % 15;
    int n = t / 15;
    int co = half * 64 + lane;

    uint32_t wq0[9], wq1[9];
#pragma unroll
    for (int tap = 0; tap < 9; tap++) {
        wq0[tap] = w3p[(tap * 2 + 0) * 128 + co];
        wq1[tap] = w3p[(tap * 2 + 1) * 128 + co];
    }
    float th = thr3[co];

    unsigned long long bals[2];
    if (ph > 0 && pwg > 0) {
        int row0 = 2 * ph - 1, col0 = 4 * pwg - 1;
        uint2 win[4][6];
#pragma unroll
        for (int r = 0; r < 4; r++)
#pragma unroll
            for (int c = 0; c < 6; c++)
                win[r][c] = y2p[(n * 31 + row0 + r) * 31 + min(col0 + c, 30)];
#pragma unroll
        for (int p = 0; p < 2; p++) {
            int a0 = 0, a1 = 0, a2 = 0, a3 = 0;
#pragma unroll
            for (int kh = 0; kh < 3; kh++)
#pragma unroll
                for (int kw = 0; kw < 3; kw++) {
                    int tap = kh * 3 + kw;
                    uint32_t u0 = wq0[tap], u1 = wq1[tap];
                    a0 += __popc(win[kh][2 * p + kw].x ^ u0) + __popc(win[kh][2 * p + kw].y ^ u1);
                    a1 += __popc(win[kh][2 * p + kw + 1].x ^ u0) + __popc(win[kh][2 * p + kw + 1].y ^ u1);
                    a2 += __popc(win[kh + 1][2 * p + kw].x ^ u0) + __popc(win[kh + 1][2 * p + kw].y ^ u1);
                    a3 += __popc(win[kh + 1][2 * p + kw + 1].x ^ u0) + __popc(win[kh + 1][2 * p + kw + 1].y ^ u1);
                }
            int best = 576 - 2 * min(min(a0, a1), min(a2, a3));
            bals[p] = __ballot((float)best < th);
        }
    } else {
#pragma unroll
        for (int p = 0; p < 2; p++) {
            int pw = 2 * pwg + p;
            int best = -1000000;
            if (pw < 15) {
#pragma unroll
                for (int dy = 0; dy < 2; dy++)
#pragma unroll
                    for (int dx = 0; dx < 2; dx++) {
                        int oh = 2 * ph + dy, ow = 2 * pw + dx;
                        int acc = 0, K = 0;
                        for (int kh = 0; kh < 3; kh++) {
                            int ih = oh - 1 + kh;
                            if (ih < 0 || ih >= 31) continue;
                            for (int kw = 0; kw < 3; kw++) {
                                int iw = ow - 1 + kw;
                                if (iw < 0 || iw >= 31) continue;
                                uint2 iv = y2p[(n * 31 + ih) * 31 + iw];
                                int tap = kh * 3 + kw;
                                acc += __popc(iv.x ^ wq0[tap]) + __popc(iv.y ^ wq1[tap]);
                                K += 64;
                            }
                        }
                        best = max(best, K - 2 * acc);
                    }
            }
            bals[p] = __ballot((float)best < th);
        }
    }
    uint32_t val = (uint32_t)bals[0];
    if (lane == 1) val = (uint32_t)(bals[0] >> 32);
    if (lane == 2) val = (uint32_t)bals[1];
    if (lane == 3) val = (uint32_t)(bals[1] >> 32);
    int p = lane >> 1;
    int pw = 2 * pwg + p;
    if (lane < 4 && pw < 15) {
        int pixel = (n * 15 + ph) * 15 + pw;
        y3p[pixel * 4 + half * 2 + (lane & 1)] = val;
    }
}

// ============================================================
// Layer 4: bconv(SAME, 15x15, CIN=128) + maxpool2 + bn -> f32 out
// Block per pixel; wave = one co-quad (co = wave*64 + lane).
// ============================================================
__global__ __launch_bounds__(256) void bconv4(const uint4* __restrict__ y3p,
                                              const uint32_t* __restrict__ w4p,
                                              const float* __restrict__ m,
                                              const float* __restrict__ v,
                                              const float* __restrict__ b,
                                              float* __restrict__ out) {
    int pixel = blockIdx.x;
    int lane = threadIdx.x & 63;
    int co = (threadIdx.x >> 6) * 64 + lane;
    int pw = pixel % 7;
    int t = pixel / 7;
    int ph = t % 7;
    int n = t / 7;

    uint4 wq[9];
#pragma unroll
    for (int tap = 0; tap < 9; tap++) {
        wq[tap].x = w4p[(tap * 4 + 0) * 256 + co];
        wq[tap].y = w4p[(tap * 4 + 1) * 256 + co];
        wq[tap].z = w4p[(tap * 4 + 2) * 256 + co];
        wq[tap].w = w4p[(tap * 4 + 3) * 256 + co];
    }
    int best;
    if (ph > 0 && pw > 0) {
        const uint4* p = y3p + (n * 15 + (2 * ph - 1)) * 15 + (2 * pw - 1);
        int a0 = 0, a1 = 0, a2 = 0, a3 = 0;
#pragma unroll
        for (int rr = 0; rr < 4; rr++)
#pragma unroll
            for (int cc = 0; cc < 4; cc++) {
                uint4 iv = p[rr * 15 + cc];
#pragma unroll
                for (int kh = 0; kh < 3; kh++) {
                    int dy = rr - kh;
                    if (dy < 0 || dy > 1) continue;
#pragma unroll
                    for (int kw = 0; kw < 3; kw++) {
                        int dx = cc - kw;
                        if (dx < 0 || dx > 1) continue;
                        int tap = kh * 3 + kw;
                        int pc = __popc(iv.x ^ wq[tap].x) + __popc(iv.y ^ wq[tap].y)
                               + __popc(iv.z ^ wq[tap].z) + __popc(iv.w ^ wq[tap].w);
                        if (dy == 0 && dx == 0) a0 += pc;
                        else if (dy == 0) a1 += pc;
                        else if (dx == 0) a2 += pc;
                        else a3 += pc;
                    }
                }
            }
        best = 1152 - 2 * min(min(a0, a1), min(a2, a3));
    } else {
        best = -1000000;
#pragma unroll
        for (int dy = 0; dy < 2; dy++)
#pragma unroll
            for (int dx = 0; dx < 2; dx++) {
                int oh = 2 * ph + dy, ow = 2 * pw + dx;
                int acc = 0, K = 0;
                for (int kh = 0; kh < 3; kh++) {
                    int ih = oh - 1 + kh;
                    if (ih < 0 || ih >= 15) continue;
                    for (int kw = 0; kw < 3; kw++) {
                        int iw = ow - 1 + kw;
                        if (iw < 0 || iw >= 15) continue;
                        uint4 iv = y3p[(n * 15 + ih) * 15 + iw];
                        int tap = kh * 3 + kw;
                        acc += __popc(iv.x ^ wq[tap].x) + __popc(iv.y ^ wq[tap].y)
                             + __popc(iv.z ^ wq[tap].z) + __popc(iv.w ^ wq[tap].w);
                        K += 128;
                    }
                }
                best = max(best, K - 2 * acc);
            }
    }
    float y = ((float)best - m[co]) * rsqrtf(v[co] + BN_EPS) + b[co];
    out[pixel * 256 + co] = y;
}

extern "C" void kernel_launch(void* const* d_in, const int* in_sizes, int n_in,
                              void* d_out, int out_size, void* d_ws, size_t ws_size,
                              hipStream_t stream) {
    const float* x  = (const float*)d_in[0];
    const float* w1 = (const float*)d_in[1];
    const float* m1 = (const float*)d_in[2];
    const float* v1 = (const float*)d_in[3];
    const float* b1 = (const float*)d_in[4];
    const float* w2 = (const float*)d_in[5];
    const float* m2 = (const float*)d_in[6];
    const float* v2 = (const float*)d_in[7];
    const float* b2 = (const float*)d_in[8];
    const float* w3 = (const float*)d_in[9];
    const float* m3 = (const float*)d_in[10];
    const float* v3 = (const float*)d_in[11];
    const float* b3 = (const float*)d_in[12];
    const float* w4 = (const float*)d_in[13];
    const float* m4 = (const float*)d_in[14];
    const float* v4 = (const float*)d_in[15];
    const float* b4 = (const float*)d_in[16];
    float* outp = (float*)d_out;

    char* ws = (char*)d_ws;
    size_t off = 0;
    auto take = [&](size_t bytes) -> char* {
        char* p = ws + off;
        off += (bytes + 255) & ~(size_t)255;
        return p;
    };
    uint32_t* y1p  = (uint32_t*)take((size_t)64 * 63 * 63 * 4);
    uint2*    y2p  = (uint2*)take((size_t)64 * 31 * 31 * 8);
    uint32_t* y3p  = (uint32_t*)take((size_t)64 * 15 * 15 * 16);
    uint32_t* w2p  = (uint32_t*)take(576 * 4);
    float*    thr2 = (float*)take(64 * 4);
    uint32_t* w3p  = (uint32_t*)take(2304 * 4);
    float*    thr3 = (float*)take(128 * 4);
    uint32_t* w4p  = (uint32_t*)take(9216 * 4);

    // conv1 (2048 blocks of 128) + layer2-4 weight prep (96 blocks: 12288 items)
    conv1_k<<<2048 + 96, 128, 0, stream>>>(
        x, w1, m1, v1, b1, w2, m2, v2, b2, w3, m3, v3, b3, w4,
        y1p, w2p, thr2, w3p, thr3, w4p);

    bconv2<<<(64 * 31 * 8) / 4, 256, 0, stream>>>(y1p, w2p, thr2, y2p);

    bconv3<<<(64 * 15 * 8 * 2) / 4, 256, 0, stream>>>(y2p, w3p, thr3, y3p);

    bconv4<<<64 * 7 * 7, 256, 0, stream>>>((const uint4*)y3p, w4p, m4, v4, b4, outp);
}